// Round 6
// baseline (404.560 us; speedup 1.0000x reference)
//
#include <hip/hip_runtime.h>

// Shapes fixed by the reference: B=8, C=128, H=W=64 -> S=4096. All I/O fp32.
#define BB 8
#define CC 128
#define SS 4096
#define KT 64
#define NSPLIT 2
#define HALF (SS / NSPLIT)     // 2048 kv tokens per split
#define ITERS (HALF / KT)      // 32
#define SCALE 0.015625f        // 1/sqrt(H*W) = 1/64

typedef __attribute__((ext_vector_type(8))) short sh8;   // 8 bf16 (MFMA A/B frag)
typedef __attribute__((ext_vector_type(4))) float f32x4; // MFMA C/D frag

__device__ __forceinline__ float b2f(unsigned short u) {
    union { unsigned int i; float f; } x; x.i = ((unsigned int)u) << 16; return x.f;
}
__device__ __forceinline__ unsigned short f2b(float f) {  // RNE
    union { float f; unsigned int i; } x; x.f = f;
    unsigned int r = x.i + 0x7fff + ((x.i >> 16) & 1);
    return (unsigned short)(r >> 16);
}
__device__ __forceinline__ unsigned short rhu(float f) {  // round-half-up, 2 VALU
    union { float f; unsigned int i; } x; x.f = f;
    return (unsigned short)((x.i + 0x8000) >> 16);
}

// async 16B global->LDS DMA (lane i writes lds_base + i*16; LDS base wave-uniform)
__device__ __forceinline__ void dma16(const void* g, void* l) {
    __builtin_amdgcn_global_load_lds((const __attribute__((address_space(1))) void*)g,
                                     (__attribute__((address_space(3))) void*)l,
                                     16, 0, 0);
}

// ---------------------------------------------------------------------------
// Fused aux. grid=(64,8,3): z=0 Q-proj, z=1 K-proj (LDS img staging, inline
// W fp32->bf16), z=2 V fp32->bf16 convert (512 linear blocks).
// proj: outTok[b][s][o] = sum_c img[b][c][s]*W[o][c] + bias[o]  (bf16 out)
// ---------------------------------------------------------------------------
__global__ __launch_bounds__(256) void aux_kernel(
    const float* __restrict__ qimg, const float* __restrict__ kimg,
    const float* __restrict__ vimg,
    const float* __restrict__ Wq, const float* __restrict__ bq,
    const float* __restrict__ Wk, const float* __restrict__ bk,
    unsigned short* __restrict__ Qbuf, unsigned short* __restrict__ Kbuf,
    unsigned short* __restrict__ Vbuf)
{
    const int tid = threadIdx.x;
    const int z   = blockIdx.z;

    if (z == 2) {
        const size_t base = ((size_t)blockIdx.y * 64 + blockIdx.x) * 8192 + tid * 4;
        #pragma unroll
        for (int it = 0; it < 8; ++it) {
            const size_t i = base + (size_t)it * 1024;
            float4 v = *(const float4*)(vimg + i);
            ushort4 o;
            o.x = f2b(v.x); o.y = f2b(v.y); o.z = f2b(v.z); o.w = f2b(v.w);
            *(ushort4*)(Vbuf + i) = o;
        }
        return;
    }

    __shared__ float ilds[128 * 69];   // 128 chans x (64 tok + 5 pad) = 35,328 B

    const float* img  = (z == 0) ? qimg : kimg;
    const float* Wf   = (z == 0) ? Wq : Wk;
    const float* bias = (z == 0) ? bq : bk;
    unsigned short* outTok = (z == 0) ? Qbuf : Kbuf;

    const int wave = tid >> 6;
    const int lane = tid & 63;
    const int l15  = lane & 15;
    const int quad = lane >> 4;
    const int b     = blockIdx.y;
    const int stile = blockIdx.x;

    // stage 128x64 fp32 tile, coalesced (256B contiguous per 16 lanes)
    const float* gbase = img + (size_t)b * CC * SS + stile * 64;
    #pragma unroll
    for (int i = 0; i < 8; ++i) {
        const int l = tid + 256 * i;          // 0..2047
        const int row = l >> 4, col = (l & 15) * 4;
        float4 v = *(const float4*)(gbase + (size_t)row * SS + col);
        float* d = ilds + row * 69 + col;
        d[0] = v.x; d[1] = v.y; d[2] = v.z; d[3] = v.w;
    }
    __syncthreads();

    // A-frags from LDS (2-way bank aliasing only with pad 69)
    const int tcol = wave * 16 + l15;
    sh8 a[4];
    #pragma unroll
    for (int kk = 0; kk < 4; ++kk)
        #pragma unroll
        for (int j = 0; j < 8; ++j)
            a[kk][j] = (short)rhu(ilds[(32 * kk + quad * 8 + j) * 69 + tcol]);

    f32x4 acc[8];
    #pragma unroll
    for (int nt = 0; nt < 8; ++nt) acc[nt] = (f32x4){0.f, 0.f, 0.f, 0.f};

    #pragma unroll
    for (int nt = 0; nt < 8; ++nt) {
        const float* wp = Wf + (size_t)(16 * nt + l15) * CC + quad * 8;
        #pragma unroll
        for (int kk = 0; kk < 4; ++kk) {
            float4 w0 = *(const float4*)(wp + 32 * kk);
            float4 w1 = *(const float4*)(wp + 32 * kk + 4);
            sh8 bfr;
            bfr[0] = (short)rhu(w0.x); bfr[1] = (short)rhu(w0.y);
            bfr[2] = (short)rhu(w0.z); bfr[3] = (short)rhu(w0.w);
            bfr[4] = (short)rhu(w1.x); bfr[5] = (short)rhu(w1.y);
            bfr[6] = (short)rhu(w1.z); bfr[7] = (short)rhu(w1.w);
            acc[nt] = __builtin_amdgcn_mfma_f32_16x16x32_bf16(a[kk], bfr, acc[nt], 0, 0, 0);
        }
    }

    #pragma unroll
    for (int nt = 0; nt < 8; ++nt) {
        const int o = 16 * nt + l15;
        const float bv = bias[o];
        #pragma unroll
        for (int r = 0; r < 4; ++r) {
            const int s = stile * 64 + wave * 16 + quad * 4 + r;
            outTok[((size_t)b * SS + s) * CC + o] = f2b(acc[nt][r] + bv);
        }
    }
}

// ---------------------------------------------------------------------------
// Flash attention, KV-split x2. grid=(64,8,2) = 1024 blocks = 4 blocks/CU
// (LDS 40960 x 4 = exactly 160 KiB). No-max softmax => partials are additive:
// each split writes bf16 partial O + fp32 partial l; ticket decides which
// block combines (no spin: first-done exits, second-done finalizes).
// LDS map: [0,16K) K  [16K,32K) V  [32K,40K) P  (all XOR chunk-swizzled).
// ---------------------------------------------------------------------------
__global__ __launch_bounds__(256, 4) void attn_kernel(
    const unsigned short* __restrict__ Qbuf,  // (B,S,C) bf16 token-major
    const unsigned short* __restrict__ Kbuf,  // (B,S,C) bf16 token-major
    const unsigned short* __restrict__ Vbuf,  // (B,C,S) bf16 channel-major
    unsigned short* __restrict__ pO,          // (2*512, 64, 128) bf16 partial O
    float* __restrict__ pl,                   // (2*512, 64) fp32 partial l
    int* __restrict__ tickets,                // (512) zeroed before launch
    float* __restrict__ out)                  // (B,C,S) fp32 channel-major
{
    __shared__ __align__(16) unsigned char smem[40960];
    unsigned char* kb = smem;
    unsigned char* vb = smem + 16384;

    const int tid  = threadIdx.x;
    const int wave = tid >> 6;
    const int lane = tid & 63;
    const int l15  = lane & 15;
    const int quad = lane >> 4;
    const int b     = blockIdx.y;
    const int qtile = blockIdx.x;
    const int split = blockIdx.z;
    const int qbase = qtile * 64 + wave * 16;

    unsigned char* pw = smem + 32768 + wave * 2048;  // this wave's P (16 x 128 B)

    const unsigned short* kbp = Kbuf + (size_t)b * SS * CC + (size_t)split * HALF * CC;
    const unsigned short* vbp = Vbuf + (size_t)b * CC * SS + split * HALF;

    // Q A-frags, loaded once from global
    sh8 aq[4];
    {
        const unsigned short* qp = Qbuf + ((size_t)b * SS + qbase + l15) * CC + quad * 8;
        #pragma unroll
        for (int kk = 0; kk < 4; ++kk) aq[kk] = *(const sh8*)(qp + 32 * kk);
    }

    // per-lane DMA source offsets (bytes), constant across iterations
    int kGO[4], vGO[4];
    #pragma unroll
    for (int j = 0; j < 4; ++j) {
        const int krow = wave * 16 + j * 4 + (lane >> 4);
        kGO[j] = krow * 256 + (((lane & 15) ^ (krow & 7)) << 4);
        const int vrow = (wave * 4 + j) * 8 + (lane >> 3);
        vGO[j] = vrow * 8192 + (((lane & 7) ^ ((lane >> 3) & 7)) << 4);
    }

    f32x4 oacc[8];
    #pragma unroll
    for (int ct = 0; ct < 8; ++ct) oacc[ct] = (f32x4){0.f, 0.f, 0.f, 0.f};
    float lsum[4] = {0.f, 0.f, 0.f, 0.f};

    // prologue: stage K(0), V(0) of this split
    #pragma unroll
    for (int j = 0; j < 4; ++j) {
        dma16((const char*)kbp + kGO[j], kb + (wave * 4 + j) * 1024);
        dma16((const char*)vbp + vGO[j], vb + (wave * 4 + j) * 1024);
    }

    for (int it = 0; it < ITERS; ++it) {
        __syncthreads();   // (a) K/V tiles resident

        // --- S = Q K^T from LDS K tile ---
        f32x4 sacc[4];
        #pragma unroll
        for (int n = 0; n < 4; ++n) {
            sacc[n] = (f32x4){0.f, 0.f, 0.f, 0.f};
            #pragma unroll
            for (int kk = 0; kk < 4; ++kk) {
                sh8 kf = *(const sh8*)(kb + (16 * n + l15) * 256
                                          + (((4 * kk + quad) ^ (l15 & 7)) << 4));
                sacc[n] = __builtin_amdgcn_mfma_f32_16x16x32_bf16(aq[kk], kf, sacc[n], 0, 0, 0);
            }
        }

        // --- unnormalized softmax -> swizzled P ---
        #pragma unroll
        for (int n = 0; n < 4; ++n)
            #pragma unroll
            for (int r = 0; r < 4; ++r) {
                float p = __expf(sacc[n][r] * SCALE);
                lsum[r] += p;
                const int row = quad * 4 + r, col = 16 * n + l15;
                *(unsigned short*)(pw + row * 128
                                   + (((col >> 3) ^ (row & 7)) << 4)
                                   + (col & 7) * 2) = rhu(p);
            }

        // --- PV ks=0 from LDS ---
        sh8 ap0 = *(const sh8*)(pw + l15 * 128 + ((quad ^ (l15 & 7)) << 4));
        #pragma unroll
        for (int ct = 0; ct < 8; ++ct) {
            sh8 bv = *(const sh8*)(vb + (16 * ct + l15) * 128
                                      + ((quad ^ (l15 & 7)) << 4));
            oacc[ct] = __builtin_amdgcn_mfma_f32_16x16x32_bf16(ap0, bv, oacc[ct], 0, 0, 0);
        }

        // --- preload ks=1 operands to registers ---
        sh8 ap1 = *(const sh8*)(pw + l15 * 128 + (((4 + quad) ^ (l15 & 7)) << 4));
        sh8 vv[8];
        #pragma unroll
        for (int ct = 0; ct < 8; ++ct)
            vv[ct] = *(const sh8*)(vb + (16 * ct + l15) * 128
                                      + (((4 + quad) ^ (l15 & 7)) << 4));

        __syncthreads();   // (b) all waves done reading K/V/P

        // --- issue next-tile DMA (overlaps PV ks=1 + other blocks) ---
        if (it + 1 < ITERS) {
            const char* gk = (const char*)kbp + (size_t)(it + 1) * KT * 256;
            const char* gv = (const char*)vbp + (size_t)(it + 1) * KT * 2;
            #pragma unroll
            for (int j = 0; j < 4; ++j) {
                dma16(gk + kGO[j], kb + (wave * 4 + j) * 1024);
                dma16(gv + vGO[j], vb + (wave * 4 + j) * 1024);
            }
        }

        // --- PV ks=1 from registers ---
        #pragma unroll
        for (int ct = 0; ct < 8; ++ct)
            oacc[ct] = __builtin_amdgcn_mfma_f32_16x16x32_bf16(ap1, vv[ct], oacc[ct], 0, 0, 0);
    }

    // --- reduce lsum across the 16 lanes of each quad ---
    #pragma unroll
    for (int r = 0; r < 4; ++r) {
        float v = lsum[r];
        #pragma unroll
        for (int m = 8; m >= 1; m >>= 1) v += __shfl_xor(v, m, 64);
        lsum[r] = v;
    }

    // --- write this split's partials ---
    const int id = b * 64 + qtile;
    unsigned short* myO = pO + ((size_t)(split * 512 + id)) * 8192;
    #pragma unroll
    for (int ct = 0; ct < 8; ++ct)
        #pragma unroll
        for (int r = 0; r < 4; ++r)
            myO[(wave * 16 + quad * 4 + r) * 128 + 16 * ct + l15] = rhu(oacc[ct][r]);
    if (l15 == 0)
        #pragma unroll
        for (int r = 0; r < 4; ++r)
            pl[(split * 512 + id) * 64 + wave * 16 + quad * 4 + r] = lsum[r];

    __threadfence();       // release: partials visible device-wide
    __syncthreads();
    int* flg = (int*)smem; // K region dead; reuse 4 bytes for ticket broadcast
    if (tid == 0) *flg = atomicAdd(&tickets[id], 1);
    __syncthreads();
    if (*flg == 0) return; // first-done block exits; the other combines

    __threadfence();       // acquire side: see the other split's partials
    __syncthreads();       // all threads past flag read before smem reuse below

    // --- combine with other split, normalize, residual, transpose write ---
    const unsigned short* oO = pO + ((size_t)((1 - split) * 512 + id)) * 8192;
    const float* opl = pl + ((1 - split) * 512 + id) * 64;
    float ltot[4];
    #pragma unroll
    for (int r = 0; r < 4; ++r)
        ltot[r] = lsum[r] + opl[wave * 16 + quad * 4 + r];

    float (*oLds)[129] = (float(*)[129])smem;
    #pragma unroll
    for (int ct = 0; ct < 8; ++ct) {
        const int c = 16 * ct + l15;
        #pragma unroll
        for (int r = 0; r < 4; ++r) {
            const int qloc  = wave * 16 + quad * 4 + r;
            const int qglob = qtile * 64 + qloc;
            const float o2 = b2f(oO[qloc * 128 + c]);
            const float resid = b2f(Qbuf[((size_t)b * SS + qglob) * CC + c]);
            oLds[qloc][c] = (oacc[ct][r] + o2) / ltot[r] + resid;
        }
    }
    __syncthreads();
    for (int idx = tid; idx < 64 * 128; idx += 256) {
        const int c = idx >> 6, q = idx & 63;
        out[((size_t)b * CC + c) * SS + qtile * 64 + q] = oLds[q][c];
    }
}

extern "C" void kernel_launch(void* const* d_in, const int* in_sizes, int n_in,
                              void* d_out, int out_size, void* d_ws, size_t ws_size,
                              hipStream_t stream) {
    const float* qimg = (const float*)d_in[0];
    const float* kimg = (const float*)d_in[1];
    const float* vimg = (const float*)d_in[2];
    const float* Wq   = (const float*)d_in[3];
    const float* bq   = (const float*)d_in[4];
    const float* Wk   = (const float*)d_in[5];
    const float* bk   = (const float*)d_in[6];
    float* out = (float*)d_out;

    unsigned short* Qbuf = (unsigned short*)d_ws;                    // 8.39 MB
    unsigned short* Kbuf = Qbuf + (size_t)BB * SS * CC;              // 8.39 MB
    unsigned short* Vbuf = Kbuf + (size_t)BB * SS * CC;              // 8.39 MB
    unsigned short* pO   = Vbuf + (size_t)BB * SS * CC;              // 16.78 MB
    float* pl            = (float*)(pO + (size_t)2 * 512 * 8192);    // 262 KB
    int* tickets         = (int*)(pl + 2 * 512 * 64);                // 2 KB

    hipMemsetAsync(tickets, 0, 512 * sizeof(int), stream);
    aux_kernel<<<dim3(SS / 64, BB, 3), 256, 0, stream>>>(
        qimg, kimg, vimg, Wq, bq, Wk, bk, Qbuf, Kbuf, Vbuf);
    attn_kernel<<<dim3(SS / 64, BB, NSPLIT), 256, 0, stream>>>(
        Qbuf, Kbuf, Vbuf, pO, pl, tickets, out);
}

// Round 8
// 228.007 us; speedup vs baseline: 1.7743x; 1.7743x over previous
//
#include <hip/hip_runtime.h>

// Shapes fixed by the reference: B=8, C=128, H=W=64 -> S=4096. All I/O fp32.
#define BB 8
#define CC 128
#define SS 4096
#define KT 64
#define SCALE 0.015625f        // 1/sqrt(H*W) = 1/64

typedef __attribute__((ext_vector_type(8))) short sh8;   // 8 bf16 (MFMA A/B frag)
typedef __attribute__((ext_vector_type(4))) float f32x4; // MFMA C/D frag

__device__ __forceinline__ float b2f(unsigned short u) {
    union { unsigned int i; float f; } x; x.i = ((unsigned int)u) << 16; return x.f;
}
__device__ __forceinline__ unsigned short f2b(float f) {  // RNE
    union { float f; unsigned int i; } x; x.f = f;
    unsigned int r = x.i + 0x7fff + ((x.i >> 16) & 1);
    return (unsigned short)(r >> 16);
}
__device__ __forceinline__ unsigned short rhu(float f) {  // round-half-up, 2 VALU
    union { float f; unsigned int i; } x; x.f = f;
    return (unsigned short)((x.i + 0x8000) >> 16);
}

// async 16B global->LDS DMA (lane i writes lds_base + i*16; LDS base wave-uniform)
__device__ __forceinline__ void dma16(const void* g, void* l) {
    __builtin_amdgcn_global_load_lds((const __attribute__((address_space(1))) void*)g,
                                     (__attribute__((address_space(3))) void*)l,
                                     16, 0, 0);
}

// ---------------------------------------------------------------------------
// Fused aux. grid=(64,8,3): z=0 Q-proj, z=1 K-proj (LDS img staging, inline
// W fp32->bf16), z=2 V fp32->bf16 convert (512 linear blocks).
// proj: outTok[b][s][o] = sum_c img[b][c][s]*W[o][c] + bias[o]  (bf16 out)
// ---------------------------------------------------------------------------
__global__ __launch_bounds__(256) void aux_kernel(
    const float* __restrict__ qimg, const float* __restrict__ kimg,
    const float* __restrict__ vimg,
    const float* __restrict__ Wq, const float* __restrict__ bq,
    const float* __restrict__ Wk, const float* __restrict__ bk,
    unsigned short* __restrict__ Qbuf, unsigned short* __restrict__ Kbuf,
    unsigned short* __restrict__ Vbuf)
{
    const int tid = threadIdx.x;
    const int z   = blockIdx.z;

    if (z == 2) {
        const size_t base = ((size_t)blockIdx.y * 64 + blockIdx.x) * 8192 + tid * 4;
        #pragma unroll
        for (int it = 0; it < 8; ++it) {
            const size_t i = base + (size_t)it * 1024;
            float4 v = *(const float4*)(vimg + i);
            ushort4 o;
            o.x = f2b(v.x); o.y = f2b(v.y); o.z = f2b(v.z); o.w = f2b(v.w);
            *(ushort4*)(Vbuf + i) = o;
        }
        return;
    }

    __shared__ float ilds[128 * 69];   // 128 chans x (64 tok + 5 pad) = 35,328 B

    const float* img  = (z == 0) ? qimg : kimg;
    const float* Wf   = (z == 0) ? Wq : Wk;
    const float* bias = (z == 0) ? bq : bk;
    unsigned short* outTok = (z == 0) ? Qbuf : Kbuf;

    const int wave = tid >> 6;
    const int lane = tid & 63;
    const int l15  = lane & 15;
    const int quad = lane >> 4;
    const int b     = blockIdx.y;
    const int stile = blockIdx.x;

    // stage 128x64 fp32 tile, coalesced (64B contiguous per 16 lanes)
    const float* gbase = img + (size_t)b * CC * SS + stile * 64;
    #pragma unroll
    for (int i = 0; i < 8; ++i) {
        const int l = tid + 256 * i;          // 0..2047
        const int row = l >> 4, col = (l & 15) * 4;
        float4 v = *(const float4*)(gbase + (size_t)row * SS + col);
        float* d = ilds + row * 69 + col;
        d[0] = v.x; d[1] = v.y; d[2] = v.z; d[3] = v.w;
    }
    __syncthreads();

    // A-frags from LDS (2-way bank aliasing only with pad 69)
    const int tcol = wave * 16 + l15;
    sh8 a[4];
    #pragma unroll
    for (int kk = 0; kk < 4; ++kk)
        #pragma unroll
        for (int j = 0; j < 8; ++j)
            a[kk][j] = (short)rhu(ilds[(32 * kk + quad * 8 + j) * 69 + tcol]);

    f32x4 acc[8];
    #pragma unroll
    for (int nt = 0; nt < 8; ++nt) acc[nt] = (f32x4){0.f, 0.f, 0.f, 0.f};

    #pragma unroll
    for (int nt = 0; nt < 8; ++nt) {
        const float* wp = Wf + (size_t)(16 * nt + l15) * CC + quad * 8;
        #pragma unroll
        for (int kk = 0; kk < 4; ++kk) {
            float4 w0 = *(const float4*)(wp + 32 * kk);
            float4 w1 = *(const float4*)(wp + 32 * kk + 4);
            sh8 bfr;
            bfr[0] = (short)rhu(w0.x); bfr[1] = (short)rhu(w0.y);
            bfr[2] = (short)rhu(w0.z); bfr[3] = (short)rhu(w0.w);
            bfr[4] = (short)rhu(w1.x); bfr[5] = (short)rhu(w1.y);
            bfr[6] = (short)rhu(w1.z); bfr[7] = (short)rhu(w1.w);
            acc[nt] = __builtin_amdgcn_mfma_f32_16x16x32_bf16(a[kk], bfr, acc[nt], 0, 0, 0);
        }
    }

    #pragma unroll
    for (int nt = 0; nt < 8; ++nt) {
        const int o = 16 * nt + l15;
        const float bv = bias[o];
        #pragma unroll
        for (int r = 0; r < 4; ++r) {
            const int s = stile * 64 + wave * 16 + quad * 4 + r;
            outTok[((size_t)b * SS + s) * CC + o] = f2b(acc[nt][r] + bv);
        }
    }
}

// ---------------------------------------------------------------------------
// Flash attention: K AND V double-buffered in LDS (72 KiB), ONE barrier/iter.
// Next tile's DMA issued at iteration top -> a full iteration of compute
// (~QK+softmax+PV) covers the DMA latency before the next barrier drains it.
// grid=(64,8) = 512 blocks = 2 blocks/CU (grid-capped; 80KiB/block available).
// LDS map:
//   [0,16K)   kb0   [16K,32K) kb1    : 64 tok x 256 B, chunk swizzle ^(row&7)
//   [32K,48K) vb0   [48K,64K) vb1    : 128 ch x 128 B, chunk swizzle ^(row&7)
//   [64K,72K) P : 4 waves x (16 x 128 B), chunk swizzle ^(row&7)
//   epilogue: oLds float[64][129] aliases front (after a barrier).
// NOTE: no pointer-array to __shared__ (gfx950 static-init addrspacecast bug);
//       double-buffer bases computed by offset arithmetic each iteration.
// ---------------------------------------------------------------------------
__global__ __launch_bounds__(256, 2) void attn_kernel(
    const unsigned short* __restrict__ Qbuf,  // (B,S,C) bf16 token-major
    const unsigned short* __restrict__ Kbuf,  // (B,S,C) bf16 token-major
    const unsigned short* __restrict__ Vbuf,  // (B,C,S) bf16 channel-major
    float* __restrict__ out)                  // (B,C,S) fp32 channel-major
{
    __shared__ __align__(16) unsigned char smem[73728];

    const int tid  = threadIdx.x;
    const int wave = tid >> 6;
    const int lane = tid & 63;
    const int l15  = lane & 15;
    const int quad = lane >> 4;
    const int b     = blockIdx.y;
    const int qtile = blockIdx.x;
    const int qbase = qtile * 64 + wave * 16;

    unsigned char* pw = smem + 65536 + wave * 2048;  // this wave's P (16 x 128 B)

    const unsigned short* kbp = Kbuf + (size_t)b * SS * CC;
    const unsigned short* vbp = Vbuf + (size_t)b * CC * SS;

    // Q A-frags, loaded once from global
    sh8 aq[4];
    {
        const unsigned short* qp = Qbuf + ((size_t)b * SS + qbase + l15) * CC + quad * 8;
        #pragma unroll
        for (int kk = 0; kk < 4; ++kk) aq[kk] = *(const sh8*)(qp + 32 * kk);
    }

    // per-lane DMA source offsets (bytes), constant across iterations
    int kGO[4], vGO[4];
    #pragma unroll
    for (int j = 0; j < 4; ++j) {
        const int krow = wave * 16 + j * 4 + (lane >> 4);
        kGO[j] = krow * 256 + (((lane & 15) ^ (krow & 7)) << 4);
        const int vrow = (wave * 4 + j) * 8 + (lane >> 3);
        vGO[j] = vrow * 8192 + (((lane & 7) ^ ((lane >> 3) & 7)) << 4);
    }

    f32x4 oacc[8];
    #pragma unroll
    for (int ct = 0; ct < 8; ++ct) oacc[ct] = (f32x4){0.f, 0.f, 0.f, 0.f};
    float lsum[4] = {0.f, 0.f, 0.f, 0.f};

    // prologue: stage K(0), V(0) into buffer 0
    #pragma unroll
    for (int j = 0; j < 4; ++j) {
        dma16((const char*)kbp + kGO[j], smem + (wave * 4 + j) * 1024);
        dma16((const char*)vbp + vGO[j], smem + 32768 + (wave * 4 + j) * 1024);
    }

    for (int it = 0; it < SS / KT; ++it) {
        const int cur = (it & 1) * 16384;
        unsigned char* kb = smem + cur;
        unsigned char* vb = smem + 32768 + cur;

        __syncthreads();   // drains DMA for tile(it); syncs all waves

        // issue next tile's DMA into the other buffer — a full iteration of
        // compute lies between here and the barrier that waits on it
        if (it + 1 < SS / KT) {
            const int nxt = 16384 - cur;
            const char* gk = (const char*)kbp + (size_t)(it + 1) * KT * 256;
            const char* gv = (const char*)vbp + (size_t)(it + 1) * KT * 2;
            #pragma unroll
            for (int j = 0; j < 4; ++j) {
                dma16(gk + kGO[j], smem + nxt + (wave * 4 + j) * 1024);
                dma16(gv + vGO[j], smem + 32768 + nxt + (wave * 4 + j) * 1024);
            }
        }

        // --- S = Q K^T from LDS K tile ---
        f32x4 sacc[4];
        #pragma unroll
        for (int n = 0; n < 4; ++n) {
            sacc[n] = (f32x4){0.f, 0.f, 0.f, 0.f};
            #pragma unroll
            for (int kk = 0; kk < 4; ++kk) {
                sh8 kf = *(const sh8*)(kb + (16 * n + l15) * 256
                                          + (((4 * kk + quad) ^ (l15 & 7)) << 4));
                sacc[n] = __builtin_amdgcn_mfma_f32_16x16x32_bf16(aq[kk], kf, sacc[n], 0, 0, 0);
            }
        }

        // --- unnormalized softmax -> swizzled P ---
        #pragma unroll
        for (int n = 0; n < 4; ++n)
            #pragma unroll
            for (int r = 0; r < 4; ++r) {
                float p = __expf(sacc[n][r] * SCALE);
                lsum[r] += p;
                const int row = quad * 4 + r, col = 16 * n + l15;
                *(unsigned short*)(pw + row * 128
                                   + (((col >> 3) ^ (row & 7)) << 4)
                                   + (col & 7) * 2) = rhu(p);
            }

        // --- PV: both halves straight from LDS ---
        #pragma unroll
        for (int ks = 0; ks < 2; ++ks) {
            sh8 ap = *(const sh8*)(pw + l15 * 128
                                   + (((4 * ks + quad) ^ (l15 & 7)) << 4));
            #pragma unroll
            for (int ct = 0; ct < 8; ++ct) {
                sh8 bv = *(const sh8*)(vb + (16 * ct + l15) * 128
                                          + (((4 * ks + quad) ^ (l15 & 7)) << 4));
                oacc[ct] = __builtin_amdgcn_mfma_f32_16x16x32_bf16(ap, bv, oacc[ct], 0, 0, 0);
            }
        }
    }

    // --- reduce lsum across the 16 lanes of each quad ---
    #pragma unroll
    for (int r = 0; r < 4; ++r) {
        float v = lsum[r];
        #pragma unroll
        for (int m = 8; m >= 1; m >>= 1) v += __shfl_xor(v, m, 64);
        lsum[r] = v;
    }

    __syncthreads();   // all waves done reading K/V LDS before aliasing it

    // --- epilogue: normalize, residual, coalesced transpose write ---
    float (*oLds)[129] = (float(*)[129])smem;
    #pragma unroll
    for (int ct = 0; ct < 8; ++ct) {
        const int c = 16 * ct + l15;
        #pragma unroll
        for (int r = 0; r < 4; ++r) {
            const int qloc  = wave * 16 + quad * 4 + r;
            const int qglob = qtile * 64 + qloc;
            const float resid = b2f(Qbuf[((size_t)b * SS + qglob) * CC + c]);
            oLds[qloc][c] = oacc[ct][r] / lsum[r] + resid;
        }
    }
    __syncthreads();
    for (int idx = tid; idx < 64 * 128; idx += 256) {
        const int c = idx >> 6, q = idx & 63;
        out[((size_t)b * CC + c) * SS + qtile * 64 + q] = oLds[q][c];
    }
}

extern "C" void kernel_launch(void* const* d_in, const int* in_sizes, int n_in,
                              void* d_out, int out_size, void* d_ws, size_t ws_size,
                              hipStream_t stream) {
    const float* qimg = (const float*)d_in[0];
    const float* kimg = (const float*)d_in[1];
    const float* vimg = (const float*)d_in[2];
    const float* Wq   = (const float*)d_in[3];
    const float* bq   = (const float*)d_in[4];
    const float* Wk   = (const float*)d_in[5];
    const float* bk   = (const float*)d_in[6];
    float* out = (float*)d_out;

    unsigned short* Qbuf = (unsigned short*)d_ws;                    // 8.39 MB
    unsigned short* Kbuf = Qbuf + (size_t)BB * SS * CC;              // 8.39 MB
    unsigned short* Vbuf = Kbuf + (size_t)BB * SS * CC;              // 8.39 MB

    aux_kernel<<<dim3(SS / 64, BB, 3), 256, 0, stream>>>(
        qimg, kimg, vimg, Wq, bq, Wk, bk, Qbuf, Kbuf, Vbuf);
    attn_kernel<<<dim3(SS / 64, BB), 256, 0, stream>>>(Qbuf, Kbuf, Vbuf, out);
}